// Round 12
// baseline (133.501 us; speedup 1.0000x reference)
//
#include <hip/hip_runtime.h>
#include <stdint.h>

#define BI 128
#define BT 128
#define RR 36
#define WW 50
#define DD 1024
#define NN 6400       /* fg row stride, static */
#define SEPS 1e-6f
#define L2E20 28.853900817779268f   /* 20/ln2 */

typedef __attribute__((ext_vector_type(8))) short short8v;
typedef __attribute__((ext_vector_type(4))) float float4v;
typedef __attribute__((ext_vector_type(2))) unsigned int uint2v;

__device__ __forceinline__ unsigned short f2bf(float f){
  unsigned u = __float_as_uint(f);
  return (unsigned short)((u + 0x7FFFu + ((u >> 16) & 1u)) >> 16);
}

// ---- exclusive prefix scan of il (128) and cl (128); dst[128] = total ----
__global__ __launch_bounds__(256) void prefix_kernel(
    const int* __restrict__ il, const int* __restrict__ cl,
    int* __restrict__ rowoff, int* __restrict__ coloff){
  __shared__ int buf[2][128];
  const int t = threadIdx.x;
  const int which = t >> 7, j = t & 127;
  const int v = which ? cl[j] : il[j];
  buf[which][j] = v;
  __syncthreads();
  #pragma unroll
  for (int off = 1; off < 128; off <<= 1){
    int x = (j >= off) ? buf[which][j - off] : 0;
    __syncthreads();
    buf[which][j] += x;
    __syncthreads();
  }
  int* dst = which ? coloff : rowoff;
  dst[j] = buf[which][j] - v;                 // exclusive
  if (j == 127) dst[128] = buf[which][127];   // total (M' / N')
}

// ---- gather valid rows + f32->bf16 convert. Block = one source row. ----
__global__ __launch_bounds__(256) void gather_cvt_kernel(
    const float* __restrict__ imgs, const float* __restrict__ caps,
    const int* __restrict__ il, const int* __restrict__ cl,
    const int* __restrict__ rowoff, const int* __restrict__ coloff,
    unsigned short* __restrict__ Ab, unsigned short* __restrict__ Bb){
  const int b = blockIdx.x;
  const int t = threadIdx.x;
  if (b < BI * RR){
    const int i = b / RR, r = b % RR;
    if (r >= il[i]) return;
    const float4 v = *(const float4*)(imgs + (size_t)b * DD + t * 4);
    ushort4 o = make_ushort4(f2bf(v.x), f2bf(v.y), f2bf(v.z), f2bf(v.w));
    *(ushort4*)(Ab + (size_t)(rowoff[i] + r) * DD + t * 4) = o;
  } else {
    const int bb = b - BI * RR;
    const int c = bb / WW, w = bb % WW;
    if (w >= cl[c]) return;
    const float4 v = *(const float4*)(caps + (size_t)bb * DD + t * 4);
    ushort4 o = make_ushort4(f2bf(v.x), f2bf(v.y), f2bf(v.z), f2bf(v.w));
    *(ushort4*)(Bb + (size_t)(coloff[c] + w) * DD + t * 4) = o;
  }
}

// ---- 128x128 GEMM, BK=32, triple-buffered LDS, depth-2 prefetch, compact
// grid + non-temporal C stores (validated R11). ----
__global__ __launch_bounds__(256) void gemm_kernel(
    const unsigned short* __restrict__ A, const unsigned short* __restrict__ B,
    const int* __restrict__ rowoff, const int* __restrict__ coloff,
    float* __restrict__ C){
  __shared__ __align__(16) unsigned char LDS[49152];
  const int Mp = rowoff[BI];                      // M' (runtime)
  const int Np = coloff[BT];                      // N'
  const int nnb = (Np + 127) >> 7;
  const int nact = ((Mp + 127) >> 7) * nnb;
  const int bx = blockIdx.x;
  if (bx >= nact) return;                         // compact early-exit
  const int mb = bx / nnb, nb = bx - mb * nnb;
  const int m0 = mb * 128, n0 = nb * 128;

  const int tid = threadIdx.x;
  const int lane = tid & 63, wv = tid >> 6;
  const int l15 = lane & 15, lhi = lane >> 4;
  const int wr = wv >> 1, wc = wv & 1;            // 2x2 wave grid, 64x64/wave

  // staging sources: 4 units/thread/chunk (u = j*256+tid; A: u<512, B: u>=512)
  const unsigned short* sp[4];
  #pragma unroll
  for (int j = 0; j < 4; j++){
    const int u = j * 256 + tid;
    const int v = u & 511;
    const int sup = v >> 3, slot = v & 7;
    const int sub = slot ^ (sup & 7);             // inverse of store swizzle
    const int row = sup * 2 + (sub >> 2);
    const int kg  = sub & 3;
    sp[j] = ((u < 512) ? (A + (size_t)(m0 + row) * DD)
                       : (B + (size_t)(n0 + row) * DD)) + kg * 8;
  }

  float4v acc[4][4];
  #pragma unroll
  for (int a1 = 0; a1 < 4; a1++)
    #pragma unroll
    for (int b1 = 0; b1 < 4; b1++)
      acc[a1][b1] = (float4v){0.f, 0.f, 0.f, 0.f};

#define STAGE(BUF, CH) { \
    _Pragma("unroll") \
    for (int j = 0; j < 4; j++) \
      __builtin_amdgcn_global_load_lds( \
          (const __attribute__((address_space(1))) void*)(sp[j] + (CH) * 32), \
          (__attribute__((address_space(3))) void*)(LDS + (BUF) * 16384 + (j * 256 + tid) * 16), \
          16, 0, 0); }

#define LUNIT(row) (((row) >> 1) * 8 + (((((row) & 1) << 2) + lhi) ^ (((row) >> 1) & 7)))

#define COMPUTE(BUF) { \
    short8v af[4], bf[4]; \
    _Pragma("unroll") \
    for (int tr = 0; tr < 4; tr++){ \
      const int row = wr * 64 + tr * 16 + l15; \
      af[tr] = *(const short8v*)(LDS + (BUF) * 16384 + LUNIT(row) * 16); \
    } \
    _Pragma("unroll") \
    for (int tw = 0; tw < 4; tw++){ \
      const int row = wc * 64 + tw * 16 + l15; \
      bf[tw] = *(const short8v*)(LDS + (BUF) * 16384 + 8192 + LUNIT(row) * 16); \
    } \
    _Pragma("unroll") \
    for (int tr = 0; tr < 4; tr++) \
      _Pragma("unroll") \
      for (int tw = 0; tw < 4; tw++) \
        acc[tr][tw] = __builtin_amdgcn_mfma_f32_16x16x32_bf16( \
            af[tr], bf[tw], acc[tr][tw], 0, 0, 0); }

#define WAIT8  asm volatile("s_waitcnt vmcnt(8)" ::: "memory")
#define WAIT4  asm volatile("s_waitcnt vmcnt(4)" ::: "memory")
#define WAIT0  asm volatile("s_waitcnt vmcnt(0)" ::: "memory")
#define BAR    __builtin_amdgcn_s_barrier()

  STAGE(0, 0);                    // prologue: chunks 0,1 in flight
  STAGE(1, 1);
  #pragma unroll 1
  for (int k = 0; k < 10; k++){   // chunks 3k, 3k+1, 3k+2 in bufs 0,1,2
    const int c = 3 * k;
    STAGE(2, c + 2); WAIT8; BAR; COMPUTE(0); BAR;   // compute chunk c
    STAGE(0, c + 3); WAIT8; BAR; COMPUTE(1); BAR;   // chunk c+1
    STAGE(1, c + 4); WAIT8; BAR; COMPUTE(2); BAR;   // chunk c+2
  }
  WAIT4; BAR; COMPUTE(0); BAR;    // chunk 30 (staged at k=9 step B)
  WAIT0; BAR; COMPUTE(1);         // chunk 31 (staged at k=9 step C)

#undef STAGE
#undef LUNIT
#undef COMPUTE
#undef WAIT8
#undef WAIT4
#undef WAIT0
#undef BAR

  // C/D layout: col = lane&15, row = lhi*4 + j (m89/m91, validated R1-R11).
  // Non-temporal: fg is consumed once, later, by sink — keep it out of L2.
  #pragma unroll
  for (int tr = 0; tr < 4; tr++)
    #pragma unroll
    for (int tw = 0; tw < 4; tw++)
      #pragma unroll
      for (int j = 0; j < 4; j++){
        int m = m0 + wr * 64 + tr * 16 + lhi * 4 + j;
        int n = n0 + wc * 64 + tw * 16 + l15;
        __builtin_nontemporal_store(acc[tr][tw][j], &C[(size_t)m * NN + n]);
      }
}

// ---- reduction helpers (validated R1-R11) ----
template<int CTRL>
__device__ __forceinline__ float dpp_add(float x){
  int y = __builtin_amdgcn_mov_dpp(__float_as_int(x), CTRL, 0xF, 0xF, true);
  return x + __int_as_float(y);
}
__device__ __forceinline__ float q16sum(float x){
  x = dpp_add<0x121>(x);   // row_ror:1
  x = dpp_add<0x122>(x);   // row_ror:2
  x = dpp_add<0x124>(x);   // row_ror:4
  x = dpp_add<0x128>(x);   // row_ror:8
  return x;
}
__device__ __forceinline__ float pl16comb(float x){
  unsigned xi = __float_as_uint(x);
  uint2v r = __builtin_amdgcn_permlane16_swap(xi, xi, false, false);
  return __uint_as_float(r[0]) + __uint_as_float(r[1]);
}
__device__ __forceinline__ float pl32comb(float x){
  unsigned xi = __float_as_uint(x);
  uint2v r = __builtin_amdgcn_permlane32_swap(xi, xi, false, false);
  return __uint_as_float(r[0]) + __uint_as_float(r[1]);
}

// ---- Sinkhorn body, templated on NS = live column-slot count (1..4).
// Layout (validated R8-R11): quarter q owns rows 9q..9q+8; lane (q,t) holds
// cols t+16j, j<NS. clen is wave-uniform -> dead slots are skipped at issue
// level for the WHOLE body (E[NS]=2.17 of 4 -> ~46% elementwise saving).
// All loops fully unrolled -> static indices -> p[9][NS] stays in VGPRs. ----
template<int NS>
__device__ __forceinline__ float sink_impl(
    const float* __restrict__ base, const int off0, const int r0,
    const int ilen, const int clen, const int t,
    const float inv_il, const float inv_cl){
  bool v[NS];
  #pragma unroll
  for (int j = 0; j < NS; j++) v[j] = (t + 16 * j) < clen;

  float p[9][NS];
  float ts = 0.f;
  #pragma unroll
  for (int k = 0; k < 9; k++){
    const int vo = off0 + k * NN;
    const bool rv = (r0 + k) < ilen;
    #pragma unroll
    for (int j = 0; j < NS; j++){
      const float a = base[vo + 16 * j];          // unpredicated (in-buffer)
      p[k][j] = (rv && v[j]) ? exp2f(fmaf(a, L2E20, -L2E20)) : 0.f;
      ts += p[k][j];
    }
  }
  ts = q16sum(ts);
  ts = pl16comb(ts);
  ts = pl32comb(ts);
  const float sc = __fdividef(1.0f, ts + SEPS);   // P /= (sum + EPS)
  #pragma unroll
  for (int k = 0; k < 9; k++)
    #pragma unroll
    for (int j = 0; j < NS; j++) p[k][j] *= sc;

  for (int it = 0; it < 3; it++){
    #pragma unroll
    for (int k = 0; k < 9; k++){                  // u = rowsum + EPS (4 rows/round)
      float u = p[k][0];
      #pragma unroll
      for (int j = 1; j < NS; j++) u += p[k][j];
      u = q16sum(u);
      const float rs = __fdividef(inv_il, u + SEPS);
      #pragma unroll
      for (int j = 0; j < NS; j++) p[k][j] *= rs;
    }
    float s[NS];
    #pragma unroll
    for (int j = 0; j < NS; j++) s[j] = 0.f;
    #pragma unroll
    for (int k = 0; k < 9; k++)
      #pragma unroll
      for (int j = 0; j < NS; j++) s[j] += p[k][j];
    #pragma unroll
    for (int j = 0; j < NS; j++){
      s[j] = pl16comb(s[j]);
      s[j] = pl32comb(s[j]);
      s[j] = __fdividef(inv_cl, s[j] + SEPS);     // c/v
    }
    #pragma unroll
    for (int k = 0; k < 9; k++)
      #pragma unroll
      for (int j = 0; j < NS; j++) p[k][j] *= s[j];
  }

  float sim = 0.f;
  #pragma unroll
  for (int k = 0; k < 9; k++){                    // reload f (L2/L3-hot)
    const int vo = off0 + k * NN;
    #pragma unroll
    for (int j = 0; j < NS; j++)
      sim = fmaf(base[vo + 16 * j], p[k][j], sim);
  }
  sim = q16sum(sim);
  sim = pl16comb(sim);
  sim = pl32comb(sim);
  return sim;
}

__global__ __launch_bounds__(256) void sink_kernel(
    const float* __restrict__ fg, const int* __restrict__ il,
    const int* __restrict__ cl, const int* __restrict__ rowoff,
    const int* __restrict__ coloff, float* __restrict__ out){
  const int lane = threadIdx.x & 63;
  const int gw = blockIdx.x * 4 + (threadIdx.x >> 6);   // 16384 waves
  const int i = gw >> 7, c = gw & 127;
  const int q = lane >> 4, t = lane & 15;

  const int ilen = __builtin_amdgcn_readfirstlane(il[i]);
  const int clen = __builtin_amdgcn_readfirstlane(cl[c]);
  const int ro   = __builtin_amdgcn_readfirstlane(rowoff[i]);
  const int co   = __builtin_amdgcn_readfirstlane(coloff[c]);
  const float* base = fg + (size_t)ro * NN + co;        // wave-uniform (saddr)
  const float inv_il = __fdividef(1.0f, (float)ilen);
  const float inv_cl = __fdividef(1.0f, (float)clen);
  const int r0 = 9 * q;                                 // this quarter's rows
  const int off0 = r0 * NN + t;                         // 32-bit elem offset

  // wave-uniform slot count: slot j live iff 16j < clen
  const int ns = 1 + (clen > 16) + (clen > 32) + (clen > 48);
  float sim;
  switch (ns){                                          // scalar branch
    case 1:  sim = sink_impl<1>(base, off0, r0, ilen, clen, t, inv_il, inv_cl); break;
    case 2:  sim = sink_impl<2>(base, off0, r0, ilen, clen, t, inv_il, inv_cl); break;
    case 3:  sim = sink_impl<3>(base, off0, r0, ilen, clen, t, inv_il, inv_cl); break;
    default: sim = sink_impl<4>(base, off0, r0, ilen, clen, t, inv_il, inv_cl); break;
  }
  if (lane == 0) out[i * BT + c] = sim;
}

extern "C" void kernel_launch(void* const* d_in, const int* in_sizes, int n_in,
                              void* d_out, int out_size, void* d_ws, size_t ws_size,
                              hipStream_t stream){
  const float* imgs = (const float*)d_in[0];
  const float* caps = (const float*)d_in[1];
  const int* il = (const int*)d_in[2];
  const int* cl = (const int*)d_in[3];
  float* out = (float*)d_out;

  unsigned short* Ab = (unsigned short*)d_ws;               // [4608][1024] bf16
  unsigned short* Bb = Ab + (size_t)BI * RR * DD;           // [6400][1024] bf16
  float* fg = (float*)(Bb + (size_t)BT * WW * DD);          // [4608][6400] f32
  int* rowoff = (int*)(fg + (size_t)BI * RR * NN);          // [129]
  int* coloff = rowoff + 129;                               // [129]

  prefix_kernel<<<1, 256, 0, stream>>>(il, cl, rowoff, coloff);
  gather_cvt_kernel<<<BI * RR + BT * WW, 256, 0, stream>>>(
      imgs, caps, il, cl, rowoff, coloff, Ab, Bb);
  gemm_kernel<<<36 * 50, 256, 0, stream>>>(Ab, Bb, rowoff, coloff, fg);
  sink_kernel<<<(BI * BT) / 4, 256, 0, stream>>>(fg, il, cl, rowoff, coloff, out);
}

// Round 14
// 117.434 us; speedup vs baseline: 1.1368x; 1.1368x over previous
//
#include <hip/hip_runtime.h>
#include <stdint.h>

#define BI 128
#define BT 128
#define RR 36
#define WW 50
#define DD 1024
#define NN 6400       /* fg row stride, static */
#define SEPS 1e-6f
#define L2E20 28.853900817779268f   /* 20/ln2 */

typedef __attribute__((ext_vector_type(8))) short short8v;
typedef __attribute__((ext_vector_type(4))) float float4v;
typedef __attribute__((ext_vector_type(2))) unsigned int uint2v;

__device__ __forceinline__ unsigned short f2bf(float f){
  unsigned u = __float_as_uint(f);
  return (unsigned short)((u + 0x7FFFu + ((u >> 16) & 1u)) >> 16);
}

// ---- exclusive prefix scan of il (128) and cl (128); dst[128] = total ----
__global__ __launch_bounds__(256) void prefix_kernel(
    const int* __restrict__ il, const int* __restrict__ cl,
    int* __restrict__ rowoff, int* __restrict__ coloff){
  __shared__ int buf[2][128];
  const int t = threadIdx.x;
  const int which = t >> 7, j = t & 127;
  const int v = which ? cl[j] : il[j];
  buf[which][j] = v;
  __syncthreads();
  #pragma unroll
  for (int off = 1; off < 128; off <<= 1){
    int x = (j >= off) ? buf[which][j - off] : 0;
    __syncthreads();
    buf[which][j] += x;
    __syncthreads();
  }
  int* dst = which ? coloff : rowoff;
  dst[j] = buf[which][j] - v;                 // exclusive
  if (j == 127) dst[128] = buf[which][127];   // total (M' / N')
}

// ---- gather valid rows + f32->bf16 convert. Block = one source row. ----
__global__ __launch_bounds__(256) void gather_cvt_kernel(
    const float* __restrict__ imgs, const float* __restrict__ caps,
    const int* __restrict__ il, const int* __restrict__ cl,
    const int* __restrict__ rowoff, const int* __restrict__ coloff,
    unsigned short* __restrict__ Ab, unsigned short* __restrict__ Bb){
  const int b = blockIdx.x;
  const int t = threadIdx.x;
  if (b < BI * RR){
    const int i = b / RR, r = b % RR;
    if (r >= il[i]) return;
    const float4 v = *(const float4*)(imgs + (size_t)b * DD + t * 4);
    ushort4 o = make_ushort4(f2bf(v.x), f2bf(v.y), f2bf(v.z), f2bf(v.w));
    *(ushort4*)(Ab + (size_t)(rowoff[i] + r) * DD + t * 4) = o;
  } else {
    const int bb = b - BI * RR;
    const int c = bb / WW, w = bb % WW;
    if (w >= cl[c]) return;
    const float4 v = *(const float4*)(caps + (size_t)bb * DD + t * 4);
    ushort4 o = make_ushort4(f2bf(v.x), f2bf(v.y), f2bf(v.z), f2bf(v.w));
    *(ushort4*)(Bb + (size_t)(coloff[c] + w) * DD + t * 4) = o;
  }
}

// ---- 128x128 GEMM, BK=32, triple-buffered LDS, depth-2 prefetch, compact
// grid + non-temporal C stores (validated R11). ----
__global__ __launch_bounds__(256) void gemm_kernel(
    const unsigned short* __restrict__ A, const unsigned short* __restrict__ B,
    const int* __restrict__ rowoff, const int* __restrict__ coloff,
    float* __restrict__ C){
  __shared__ __align__(16) unsigned char LDS[49152];
  const int Mp = rowoff[BI];                      // M' (runtime)
  const int Np = coloff[BT];                      // N'
  const int nnb = (Np + 127) >> 7;
  const int nact = ((Mp + 127) >> 7) * nnb;
  const int bx = blockIdx.x;
  if (bx >= nact) return;                         // compact early-exit
  const int mb = bx / nnb, nb = bx - mb * nnb;
  const int m0 = mb * 128, n0 = nb * 128;

  const int tid = threadIdx.x;
  const int lane = tid & 63, wv = tid >> 6;
  const int l15 = lane & 15, lhi = lane >> 4;
  const int wr = wv >> 1, wc = wv & 1;            // 2x2 wave grid, 64x64/wave

  // staging sources: 4 units/thread/chunk (u = j*256+tid; A: u<512, B: u>=512)
  const unsigned short* sp[4];
  #pragma unroll
  for (int j = 0; j < 4; j++){
    const int u = j * 256 + tid;
    const int v = u & 511;
    const int sup = v >> 3, slot = v & 7;
    const int sub = slot ^ (sup & 7);             // inverse of store swizzle
    const int row = sup * 2 + (sub >> 2);
    const int kg  = sub & 3;
    sp[j] = ((u < 512) ? (A + (size_t)(m0 + row) * DD)
                       : (B + (size_t)(n0 + row) * DD)) + kg * 8;
  }

  float4v acc[4][4];
  #pragma unroll
  for (int a1 = 0; a1 < 4; a1++)
    #pragma unroll
    for (int b1 = 0; b1 < 4; b1++)
      acc[a1][b1] = (float4v){0.f, 0.f, 0.f, 0.f};

#define STAGE(BUF, CH) { \
    _Pragma("unroll") \
    for (int j = 0; j < 4; j++) \
      __builtin_amdgcn_global_load_lds( \
          (const __attribute__((address_space(1))) void*)(sp[j] + (CH) * 32), \
          (__attribute__((address_space(3))) void*)(LDS + (BUF) * 16384 + (j * 256 + tid) * 16), \
          16, 0, 0); }

#define LUNIT(row) (((row) >> 1) * 8 + (((((row) & 1) << 2) + lhi) ^ (((row) >> 1) & 7)))

#define COMPUTE(BUF) { \
    short8v af[4], bf[4]; \
    _Pragma("unroll") \
    for (int tr = 0; tr < 4; tr++){ \
      const int row = wr * 64 + tr * 16 + l15; \
      af[tr] = *(const short8v*)(LDS + (BUF) * 16384 + LUNIT(row) * 16); \
    } \
    _Pragma("unroll") \
    for (int tw = 0; tw < 4; tw++){ \
      const int row = wc * 64 + tw * 16 + l15; \
      bf[tw] = *(const short8v*)(LDS + (BUF) * 16384 + 8192 + LUNIT(row) * 16); \
    } \
    _Pragma("unroll") \
    for (int tr = 0; tr < 4; tr++) \
      _Pragma("unroll") \
      for (int tw = 0; tw < 4; tw++) \
        acc[tr][tw] = __builtin_amdgcn_mfma_f32_16x16x32_bf16( \
            af[tr], bf[tw], acc[tr][tw], 0, 0, 0); }

#define WAIT8  asm volatile("s_waitcnt vmcnt(8)" ::: "memory")
#define WAIT4  asm volatile("s_waitcnt vmcnt(4)" ::: "memory")
#define WAIT0  asm volatile("s_waitcnt vmcnt(0)" ::: "memory")
#define BAR    __builtin_amdgcn_s_barrier()

  STAGE(0, 0);                    // prologue: chunks 0,1 in flight
  STAGE(1, 1);
  #pragma unroll 1
  for (int k = 0; k < 10; k++){   // chunks 3k, 3k+1, 3k+2 in bufs 0,1,2
    const int c = 3 * k;
    STAGE(2, c + 2); WAIT8; BAR; COMPUTE(0); BAR;   // compute chunk c
    STAGE(0, c + 3); WAIT8; BAR; COMPUTE(1); BAR;   // chunk c+1
    STAGE(1, c + 4); WAIT8; BAR; COMPUTE(2); BAR;   // chunk c+2
  }
  WAIT4; BAR; COMPUTE(0); BAR;    // chunk 30 (staged at k=9 step B)
  WAIT0; BAR; COMPUTE(1);         // chunk 31 (staged at k=9 step C)

#undef STAGE
#undef LUNIT
#undef COMPUTE
#undef WAIT8
#undef WAIT4
#undef WAIT0
#undef BAR

  // C/D layout: col = lane&15, row = lhi*4 + j (m89/m91, validated R1-R12).
  // Non-temporal: fg is consumed once, later, by sink — keep it out of L2.
  #pragma unroll
  for (int tr = 0; tr < 4; tr++)
    #pragma unroll
    for (int tw = 0; tw < 4; tw++)
      #pragma unroll
      for (int j = 0; j < 4; j++){
        int m = m0 + wr * 64 + tr * 16 + lhi * 4 + j;
        int n = n0 + wc * 64 + tw * 16 + l15;
        __builtin_nontemporal_store(acc[tr][tw][j], &C[(size_t)m * NN + n]);
      }
}

// ---- reduction helpers (validated R1-R12) ----
template<int CTRL>
__device__ __forceinline__ float dpp_add(float x){
  int y = __builtin_amdgcn_mov_dpp(__float_as_int(x), CTRL, 0xF, 0xF, true);
  return x + __int_as_float(y);
}
__device__ __forceinline__ float q16sum(float x){
  x = dpp_add<0x121>(x);   // row_ror:1
  x = dpp_add<0x122>(x);   // row_ror:2
  x = dpp_add<0x124>(x);   // row_ror:4
  x = dpp_add<0x128>(x);   // row_ror:8
  return x;
}
__device__ __forceinline__ float pl16comb(float x){
  unsigned xi = __float_as_uint(x);
  uint2v r = __builtin_amdgcn_permlane16_swap(xi, xi, false, false);
  return __uint_as_float(r[0]) + __uint_as_float(r[1]);
}
__device__ __forceinline__ float pl32comb(float x){
  unsigned xi = __float_as_uint(x);
  uint2v r = __builtin_amdgcn_permlane32_swap(xi, xi, false, false);
  return __uint_as_float(r[0]) + __uint_as_float(r[1]);
}

// ---- Sinkhorn: ONE pair per wave, 4-way row-split (R8-R11 layout), with
// SLOT pruning via wave-uniform scalar guards (R5-proven pattern — single
// code path, ONE regalloc; R12's template-switch spilled).  Quarter q owns
// rows 9q..9q+8; lane (q,t) holds cols t+16j.  Slot j>0 is processed only
// if 16j < clen (E[live slots] = 2.17/4 -> ~46% elementwise saving). ----
__global__ __launch_bounds__(256) void sink_kernel(
    const float* __restrict__ fg, const int* __restrict__ il,
    const int* __restrict__ cl, const int* __restrict__ rowoff,
    const int* __restrict__ coloff, float* __restrict__ out){
  const int lane = threadIdx.x & 63;
  const int gw = blockIdx.x * 4 + (threadIdx.x >> 6);   // 16384 waves
  const int i = gw >> 7, c = gw & 127;
  const int q = lane >> 4, t = lane & 15;

  const int ilen = __builtin_amdgcn_readfirstlane(il[i]);
  const int clen = __builtin_amdgcn_readfirstlane(cl[c]);
  const int ro   = __builtin_amdgcn_readfirstlane(rowoff[i]);
  const int co   = __builtin_amdgcn_readfirstlane(coloff[c]);
  const float* base = fg + (size_t)ro * NN + co;        // wave-uniform (saddr)
  const float inv_il = __fdividef(1.0f, (float)ilen);
  const float inv_cl = __fdividef(1.0f, (float)clen);
  const int r0 = 9 * q;                                 // this quarter's rows
  const int off0 = r0 * NN + t;                         // 32-bit elem offset

  const bool v0 = (t < clen);                           // per-lane
  const bool v1 = (t + 16 < clen);
  const bool v2 = (t + 32 < clen);
  const bool v3 = (t + 48 < clen);
  const bool s1 = (clen > 16);                          // wave-uniform guards
  const bool s2 = (clen > 32);
  const bool s3 = (clen > 48);

  float p0[9], p1[9], p2[9], p3[9];

  // ---- init: P = exp((fg-1)*20), masked; wave-total sum ----
  float ts = 0.f;
  #pragma unroll
  for (int k = 0; k < 9; k++){
    const bool rv = (r0 + k) < ilen;
    const float a = base[off0 + k * NN];
    p0[k] = (rv && v0) ? exp2f(fmaf(a, L2E20, -L2E20)) : 0.f;
    ts += p0[k];
  }
  if (s1){
    #pragma unroll
    for (int k = 0; k < 9; k++){
      const bool rv = (r0 + k) < ilen;
      const float a = base[off0 + k * NN + 16];
      p1[k] = (rv && v1) ? exp2f(fmaf(a, L2E20, -L2E20)) : 0.f;
      ts += p1[k];
    }
  }
  if (s2){
    #pragma unroll
    for (int k = 0; k < 9; k++){
      const bool rv = (r0 + k) < ilen;
      const float a = base[off0 + k * NN + 32];
      p2[k] = (rv && v2) ? exp2f(fmaf(a, L2E20, -L2E20)) : 0.f;
      ts += p2[k];
    }
  }
  if (s3){
    #pragma unroll
    for (int k = 0; k < 9; k++){
      const bool rv = (r0 + k) < ilen;
      const float a = base[off0 + k * NN + 48];
      p3[k] = (rv && v3) ? exp2f(fmaf(a, L2E20, -L2E20)) : 0.f;
      ts += p3[k];
    }
  }
  ts = q16sum(ts);
  ts = pl16comb(ts);
  ts = pl32comb(ts);
  const float sc = __fdividef(1.0f, ts + SEPS);         // P /= (sum + EPS)
  #pragma unroll
  for (int k = 0; k < 9; k++) p0[k] *= sc;
  if (s1){
    #pragma unroll
    for (int k = 0; k < 9; k++) p1[k] *= sc;
  }
  if (s2){
    #pragma unroll
    for (int k = 0; k < 9; k++) p2[k] *= sc;
  }
  if (s3){
    #pragma unroll
    for (int k = 0; k < 9; k++) p3[k] *= sc;
  }

  for (int it = 0; it < 3; it++){
    // ---- row pass: u = rowsum + EPS; P *= (1/ilen)/u ----
    float u[9];
    #pragma unroll
    for (int k = 0; k < 9; k++) u[k] = p0[k];
    if (s1){
      #pragma unroll
      for (int k = 0; k < 9; k++) u[k] += p1[k];
    }
    if (s2){
      #pragma unroll
      for (int k = 0; k < 9; k++) u[k] += p2[k];
    }
    if (s3){
      #pragma unroll
      for (int k = 0; k < 9; k++) u[k] += p3[k];
    }
    #pragma unroll
    for (int k = 0; k < 9; k++){
      const float w = q16sum(u[k]);
      u[k] = __fdividef(inv_il, w + SEPS);              // rs for 4 rows at once
    }
    #pragma unroll
    for (int k = 0; k < 9; k++) p0[k] *= u[k];
    if (s1){
      #pragma unroll
      for (int k = 0; k < 9; k++) p1[k] *= u[k];
    }
    if (s2){
      #pragma unroll
      for (int k = 0; k < 9; k++) p2[k] *= u[k];
    }
    if (s3){
      #pragma unroll
      for (int k = 0; k < 9; k++) p3[k] *= u[k];
    }

    // ---- col pass: v = colsum + EPS; P *= (1/clen)/v (per live slot) ----
    {
      float cs = 0.f;
      #pragma unroll
      for (int k = 0; k < 9; k++) cs += p0[k];
      cs = pl16comb(cs); cs = pl32comb(cs);
      cs = __fdividef(inv_cl, cs + SEPS);
      #pragma unroll
      for (int k = 0; k < 9; k++) p0[k] *= cs;
    }
    if (s1){
      float cs = 0.f;
      #pragma unroll
      for (int k = 0; k < 9; k++) cs += p1[k];
      cs = pl16comb(cs); cs = pl32comb(cs);
      cs = __fdividef(inv_cl, cs + SEPS);
      #pragma unroll
      for (int k = 0; k < 9; k++) p1[k] *= cs;
    }
    if (s2){
      float cs = 0.f;
      #pragma unroll
      for (int k = 0; k < 9; k++) cs += p2[k];
      cs = pl16comb(cs); cs = pl32comb(cs);
      cs = __fdividef(inv_cl, cs + SEPS);
      #pragma unroll
      for (int k = 0; k < 9; k++) p2[k] *= cs;
    }
    if (s3){
      float cs = 0.f;
      #pragma unroll
      for (int k = 0; k < 9; k++) cs += p3[k];
      cs = pl16comb(cs); cs = pl32comb(cs);
      cs = __fdividef(inv_cl, cs + SEPS);
      #pragma unroll
      for (int k = 0; k < 9; k++) p3[k] *= cs;
    }
  }

  // ---- final: sim = sum f*P (reload f; p=0 kills invalid entries) ----
  float sim = 0.f;
  #pragma unroll
  for (int k = 0; k < 9; k++)
    sim = fmaf(base[off0 + k * NN], p0[k], sim);
  if (s1){
    #pragma unroll
    for (int k = 0; k < 9; k++)
      sim = fmaf(base[off0 + k * NN + 16], p1[k], sim);
  }
  if (s2){
    #pragma unroll
    for (int k = 0; k < 9; k++)
      sim = fmaf(base[off0 + k * NN + 32], p2[k], sim);
  }
  if (s3){
    #pragma unroll
    for (int k = 0; k < 9; k++)
      sim = fmaf(base[off0 + k * NN + 48], p3[k], sim);
  }
  sim = q16sum(sim);
  sim = pl16comb(sim);
  sim = pl32comb(sim);
  if (lane == 0) out[i * BT + c] = sim;
}

extern "C" void kernel_launch(void* const* d_in, const int* in_sizes, int n_in,
                              void* d_out, int out_size, void* d_ws, size_t ws_size,
                              hipStream_t stream){
  const float* imgs = (const float*)d_in[0];
  const float* caps = (const float*)d_in[1];
  const int* il = (const int*)d_in[2];
  const int* cl = (const int*)d_in[3];
  float* out = (float*)d_out;

  unsigned short* Ab = (unsigned short*)d_ws;               // [4608][1024] bf16
  unsigned short* Bb = Ab + (size_t)BI * RR * DD;           // [6400][1024] bf16
  float* fg = (float*)(Bb + (size_t)BT * WW * DD);          // [4608][6400] f32
  int* rowoff = (int*)(fg + (size_t)BI * RR * NN);          // [129]
  int* coloff = rowoff + 129;                               // [129]

  prefix_kernel<<<1, 256, 0, stream>>>(il, cl, rowoff, coloff);
  gather_cvt_kernel<<<BI * RR + BT * WW, 256, 0, stream>>>(
      imgs, caps, il, cl, rowoff, coloff, Ab, Bb);
  gemm_kernel<<<36 * 50, 256, 0, stream>>>(Ab, Bb, rowoff, coloff, fg);
  sink_kernel<<<(BI * BT) / 4, 256, 0, stream>>>(fg, il, cl, rowoff, coloff, out);
}